// Round 10
// baseline (191.787 us; speedup 1.0000x reference)
//
#include <hip/hip_runtime.h>
#include <hip/hip_bf16.h>
#include <math.h>
#include <stdint.h>

// DynamicViewSampler — prep (m -> fragment bf16 + per-tile den) +
// GEMM (bf16 MFMA, A from ws, B staged LDS) with SPLIT-K FINISHER:
// last block per (b,dcb) (atomic counter, no spin) sums the f32 partials in
// fixed k-order + den_tile and writes out directly. No reduce kernel.
// XCD swizzle: all kblk of one (b,dcb) on one XCD -> finisher reads L2-warm.

constexpr int VV  = 64;    // views (M)
constexpr int DC  = 128;   // D cols per block (N)
constexpr int KS  = 64;    // L rows per tile
constexpr int NTH = 256;
constexpr int ST2 = 134;   // smB row stride in bf16 units (conflict-free gather)
constexpr int KCH = 8;     // chunks per batch

typedef __attribute__((ext_vector_type(8))) short short8;
typedef __attribute__((ext_vector_type(4))) float f32x4;

static __device__ __forceinline__ unsigned short f2bf(float f) {
    __hip_bfloat16 h = __float2bfloat16(f);
    return __builtin_bit_cast(unsigned short, h);
}

// ---------------- prep: m tiles (fragment order) + per-tile den + flag zero ----
__global__ __launch_bounds__(256)
void dvs_prep(const int* __restrict__ v_len, const int* __restrict__ gthw,
              const float* __restrict__ centers,
              unsigned short* __restrict__ mws,     // [B][NT][8][64] short8
              float* __restrict__ den_tile,         // [B][NT][64]
              int* __restrict__ flags,              // [B*8]
              int NT)
{
    const int t = blockIdx.x, b = blockIdx.y;
    if (t == 0 && threadIdx.x < 8)
        flags[b * 8 + threadIdx.x] = 0;            // re-zero every launch

    const int Lv = v_len[b];
    const int lt = t * KS;
    if (lt >= Lv) return;

    const float Hf = (float)gthw[b*3 + 1];
    const float Wf = (float)gthw[b*3 + 2];
    const float sq = sqrtf((float)Lv * (Wf / Hf));
    int W_eff = (int)rintf(sq);                       if (W_eff < 1) W_eff = 1;
    int H_eff = (int)ceilf((float)Lv / (float)W_eff); if (H_eff < 1) H_eff = 1;
    const float invW = 1.f / (float)W_eff, invH = 1.f / (float)H_eff;

    const int tid  = threadIdx.x;
    const int lane = tid & 63, wave = tid >> 6;
    const int ar = lane & 15, koct = lane >> 4;

    __shared__ float sden[2][4][VV];

    short8* mtile = (short8*)mws + ((size_t)b * NT + t) * 8 * 64;

#pragma unroll
    for (int i = 0; i < 2; ++i) {
        const int f  = wave * 2 + i;
        const int ks = f >> 2, mf = f & 3;
        const int v  = mf * 16 + ar;
        const float2 ctr = ((const float2*)centers)[(size_t)b * VV + v];

        int l   = lt + ks * 32 + koct * 8;
        int row = l / W_eff;
        int col = l - row * W_eff;
        float y = (float)row * invH;

        union { unsigned short h[8]; short8 s; } ap;
        float ds = 0.f;
#pragma unroll
        for (int j = 0; j < 8; ++j) {
            float m = 0.f;
            if (l + j < Lv) {
                const float x  = (float)col * invW;
                const float dx = ctr.x - x, dy = ctr.y - y;
                m = __expf(-20.f * (dx * dx + dy * dy));
            }
            ds += m;
            ap.h[j] = f2bf(m);
            if (++col == W_eff) { col = 0; ++row; y = (float)row * invH; }
        }
        mtile[f * 64 + lane] = ap.s;
        sden[ks][koct][v] = ds;           // unique (ks,koct,v) per (f,lane)
    }
    __syncthreads();
    if (tid < VV) {
        float s = 0.f;
#pragma unroll
        for (int ks = 0; ks < 2; ++ks)
#pragma unroll
            for (int q = 0; q < 4; ++q) s += sden[ks][q][tid];
        den_tile[((size_t)b * NT + t) * VV + tid] = s;
    }
}

// -------- GEMM + finisher: A from ws, B staged LDS, last block reduces --------
__global__ __launch_bounds__(NTH)
void dvs_mfma(const float* __restrict__ v_pad, const int* __restrict__ v_len,
              const unsigned short* __restrict__ mws,
              const float* __restrict__ den_tile,
              float* __restrict__ num_part,   // [B][KCH][V][D] f32
              int* __restrict__ flags,        // [B*8]
              float* __restrict__ out,
              int L, int D, int NT)
{
    // XCD swizzle: flat = kblk*128 + (b*8 + dcb) -> all kblk of (b,dcb) on
    // XCD (b*8+dcb)%8; finisher's partial reads are same-XCD-L2 warm.
    const int flat = blockIdx.x;
    const int kblk = flat >> 7;
    const int g    = flat & 127;
    const int dcb  = g & 7;
    const int b    = g >> 3;

    const int Lv = v_len[b];
    const int chunk = (((Lv + KCH - 1) / KCH) + 63) & ~63;   // 64-aligned
    const int nk = (Lv + chunk - 1) / chunk;                  // active kblks
    const int l0 = kblk * chunk;
    if (l0 >= Lv) return;
    const int l1 = min(l0 + chunk, Lv);

    const int tid  = threadIdx.x;
    const int d0   = dcb * DC;
    const int lane = tid & 63;
    const int wave = tid >> 6;

    __shared__ __align__(16) unsigned short smB[KS][ST2];   // ~16.75 KB
    __shared__ int   s_last;
    __shared__ float sinv[VV];

    const int sd   = tid & 31;    // B-staging: 32 float4 cols
    const int srow = tid >> 5;    //            8 row-groups
    const int fcol = lane & 15, foct = lane >> 4;

    f32x4 acc[4][2];
#pragma unroll
    for (int i = 0; i < 4; ++i) {
        acc[i][0] = f32x4{0.f, 0.f, 0.f, 0.f};
        acc[i][1] = f32x4{0.f, 0.f, 0.f, 0.f};
    }

    const float*  vp_b  = v_pad + (size_t)b * L * D + d0;
    const short8* mws_b = (const short8*)mws + (size_t)b * NT * 8 * 64;

    // prologue: issue tile-0 B loads
    float4 ld[8];
#pragma unroll
    for (int it = 0; it < 8; ++it) {
        const int l = l0 + it * 8 + srow;
        ld[it] = make_float4(0.f, 0.f, 0.f, 0.f);
        if (l < l1)
            ld[it] = *(const float4*)(vp_b + (size_t)l * D + sd * 4);
    }

    for (int lt = l0; lt < l1; lt += KS) {
        // ---- stage B (regs from last iteration / prologue) ----
#pragma unroll
        for (int it = 0; it < 8; ++it) {
            const int lrow = it * 8 + srow;
            unsigned* w = (unsigned*)&smB[lrow][sd * 4];
            w[0] = (unsigned)f2bf(ld[it].x) | ((unsigned)f2bf(ld[it].y) << 16);
            w[1] = (unsigned)f2bf(ld[it].z) | ((unsigned)f2bf(ld[it].w) << 16);
        }
        __syncthreads();                       // tile staged

        // ---- prefetch next tile's B globals (fly under MFMA phase) ----
        const int ltn = lt + KS;
        if (ltn < l1) {
#pragma unroll
            for (int it = 0; it < 8; ++it) {
                const int l = ltn + it * 8 + srow;
                ld[it] = make_float4(0.f, 0.f, 0.f, 0.f);
                if (l < l1)
                    ld[it] = *(const float4*)(vp_b + (size_t)l * D + sd * 4);
            }
        }

        // ---- A fragments: direct coalesced b128 loads from ws (L2/L3) ----
        const short8* mt = mws_b + ((size_t)(lt >> 6)) * 8 * 64;
        short8 af[2][4];
#pragma unroll
        for (int ks = 0; ks < 2; ++ks)
#pragma unroll
            for (int mf = 0; mf < 4; ++mf)
                af[ks][mf] = mt[(ks * 4 + mf) * 64 + lane];

        // ---- MFMA: 2 k-halves x 4 m-frags x 2 n-frags ----
#pragma unroll
        for (int ks = 0; ks < 2; ++ks) {
#pragma unroll
            for (int nf = 0; nf < 2; ++nf) {
                const int colx  = wave * 32 + nf * 16 + fcol;
                const int kbase = ks * 32 + foct * 8;
                union { unsigned short h[8]; short8 s; } bf;
#pragma unroll
                for (int j = 0; j < 8; ++j)
                    bf.h[j] = smB[kbase + j][colx];
#pragma unroll
                for (int mf = 0; mf < 4; ++mf)
                    acc[mf][nf] = __builtin_amdgcn_mfma_f32_16x16x32_bf16(
                        af[ks][mf], bf.s, acc[mf][nf], 0, 0, 0);
            }
        }
        __syncthreads();                       // MFMA reads done; smB reusable
    }

    // ---- write f32 partial (C/D: col=lane&15, row=(lane>>4)*4+r) ----
    float* basep = num_part + ((size_t)b * KCH + kblk) * VV * (size_t)D + d0 + wave * 32;
#pragma unroll
    for (int mf = 0; mf < 4; ++mf) {
#pragma unroll
        for (int nf = 0; nf < 2; ++nf) {
            const int colx = nf * 16 + fcol;
            const int row0 = mf * 16 + foct * 4;
#pragma unroll
            for (int r = 0; r < 4; ++r)
                basep[(size_t)(row0 + r) * D + colx] = acc[mf][nf][r];
        }
    }

    // ---- arrival protocol: last block per (b,dcb) becomes the finisher ----
    __threadfence();                           // partials visible device-scope
    __syncthreads();
    if (tid == 0)
        s_last = (atomicAdd(&flags[g], 1) == nk - 1);
    __syncthreads();
    if (!s_last) return;
    __threadfence();                           // acquire others' partials

    // ---- finisher: den inverse (fixed t-order) ----
    const int nt = (Lv + KS - 1) / KS;
    if (tid < VV) {
        float s = 0.f;
        const float* dt = den_tile + (size_t)b * NT * VV + tid;
        for (int t = 0; t < nt; ++t) s += dt[(size_t)t * VV];
        sinv[tid] = 1.0f / (s + 1e-6f);
    }
    __syncthreads();

    // ---- finisher: sum partials (fixed k-order) and write out ----
    const int c4 = tid & 31;                   // 32 float4 cols of this DC
    const int vb = tid >> 5;                   // 8 view groups
    const float* np_b = num_part + (size_t)b * KCH * VV * D + d0 + c4 * 4;
#pragma unroll
    for (int i = 0; i < 8; ++i) {
        const int v = vb * 8 + i;
        float4 s = make_float4(0.f, 0.f, 0.f, 0.f);
        for (int k = 0; k < nk; ++k) {
            const float4 p = *(const float4*)(np_b + ((size_t)k * VV + v) * D);
            s.x += p.x; s.y += p.y; s.z += p.z; s.w += p.w;
        }
        const float inv = sinv[v];
        *(float4*)(out + ((size_t)b * VV + v) * D + d0 + c4 * 4) =
            make_float4(s.x * inv, s.y * inv, s.z * inv, s.w * inv);
    }
}

extern "C" void kernel_launch(void* const* d_in, const int* in_sizes, int n_in,
                              void* d_out, int out_size, void* d_ws, size_t ws_size,
                              hipStream_t stream)
{
    const float* v_pad     = (const float*)d_in[0];
    const int*   v_len     = (const int*)d_in[1];
    const int*   grid_thws = (const int*)d_in[2];
    const float* centers   = (const float*)d_in[3];
    float*       out       = (float*)d_out;

    const int B  = in_sizes[1];
    const int D  = out_size / (B * VV);
    const int L  = in_sizes[0] / (B * D);
    const int NT = (L + KS - 1) / KS;

    // workspace layout (16B-aligned pieces)
    float*          num_part = (float*)d_ws;                                // B*KCH*V*D f32
    float*          den_tile = num_part + (size_t)B * KCH * VV * D;         // B*NT*V
    unsigned short* mws      = (unsigned short*)(den_tile + (size_t)B * NT * VV);
    int*            flags    = (int*)(mws + (size_t)B * NT * 8 * 64 * 8);   // B*8

    dim3 gridP(NT, B);
    dvs_prep<<<gridP, 256, 0, stream>>>(v_len, grid_thws, centers, mws,
                                        den_tile, flags, NT);

    const int nblkG = KCH * (D / DC) * B;     // 1024, XCD-swizzled decode
    dvs_mfma<<<nblkG, NTH, 0, stream>>>(v_pad, v_len, mws, den_tile,
                                        num_part, flags, out, L, D, NT);
}

// Round 11
// 45.374 us; speedup vs baseline: 4.2268x; 4.2268x over previous
//
#include <hip/hip_runtime.h>
#include <hip/hip_bf16.h>
#include <math.h>
#include <stdint.h>

// DynamicViewSampler — prep (m -> fragment bf16 + per-tile den) +
// GEMM (bf16 MFMA, A from ws, B double-buffered LDS, 1 barrier/tile) +
// reduce. Structure = round-8 (best, 42.8us) + smB ping-pong.
// Round-10 lesson: NO device-scope fences / cross-block consumption in-dispatch
// (XCD L2 writeback serializes); kernel boundary is the cheap global fence.

constexpr int VV  = 64;    // views (M)
constexpr int DC  = 128;   // D cols per block (N)
constexpr int KS  = 64;    // L rows per tile
constexpr int NTH = 256;
constexpr int ST2 = 134;   // smB row stride in bf16 units (conflict-free gather)
constexpr int KCH = 8;     // chunks per batch

typedef __attribute__((ext_vector_type(8))) short short8;
typedef __attribute__((ext_vector_type(4))) float f32x4;

static __device__ __forceinline__ unsigned short f2bf(float f) {
    __hip_bfloat16 h = __float2bfloat16(f);
    return __builtin_bit_cast(unsigned short, h);
}

// ---------------- prep: m tiles (fragment order) + per-tile den ----------------
__global__ __launch_bounds__(256)
void dvs_prep(const int* __restrict__ v_len, const int* __restrict__ gthw,
              const float* __restrict__ centers,
              unsigned short* __restrict__ mws,     // [B][NT][8][64] short8
              float* __restrict__ den_tile,         // [B][NT][64]
              int NT)
{
    const int t = blockIdx.x, b = blockIdx.y;
    const int Lv = v_len[b];
    const int lt = t * KS;
    if (lt >= Lv) return;

    const float Hf = (float)gthw[b*3 + 1];
    const float Wf = (float)gthw[b*3 + 2];
    const float sq = sqrtf((float)Lv * (Wf / Hf));
    int W_eff = (int)rintf(sq);                       if (W_eff < 1) W_eff = 1;
    int H_eff = (int)ceilf((float)Lv / (float)W_eff); if (H_eff < 1) H_eff = 1;
    const float invW = 1.f / (float)W_eff, invH = 1.f / (float)H_eff;

    const int tid  = threadIdx.x;
    const int lane = tid & 63, wave = tid >> 6;
    const int ar = lane & 15, koct = lane >> 4;

    __shared__ float sden[2][4][VV];

    short8* mtile = (short8*)mws + ((size_t)b * NT + t) * 8 * 64;

#pragma unroll
    for (int i = 0; i < 2; ++i) {
        const int f  = wave * 2 + i;
        const int ks = f >> 2, mf = f & 3;
        const int v  = mf * 16 + ar;
        const float2 ctr = ((const float2*)centers)[(size_t)b * VV + v];

        int l   = lt + ks * 32 + koct * 8;
        int row = l / W_eff;
        int col = l - row * W_eff;
        float y = (float)row * invH;

        union { unsigned short h[8]; short8 s; } ap;
        float ds = 0.f;
#pragma unroll
        for (int j = 0; j < 8; ++j) {
            float m = 0.f;
            if (l + j < Lv) {
                const float x  = (float)col * invW;
                const float dx = ctr.x - x, dy = ctr.y - y;
                m = __expf(-20.f * (dx * dx + dy * dy));
            }
            ds += m;
            ap.h[j] = f2bf(m);
            if (++col == W_eff) { col = 0; ++row; y = (float)row * invH; }
        }
        mtile[f * 64 + lane] = ap.s;
        sden[ks][koct][v] = ds;           // unique (ks,koct,v) per (f,lane)
    }
    __syncthreads();
    if (tid < VV) {
        float s = 0.f;
#pragma unroll
        for (int ks = 0; ks < 2; ++ks)
#pragma unroll
            for (int q = 0; q < 4; ++q) s += sden[ks][q][tid];
        den_tile[((size_t)b * NT + t) * VV + tid] = s;
    }
}

// ------ GEMM: A from ws (global b128), B double-buffered LDS, 1 bar/tile ------
__global__ __launch_bounds__(NTH)
void dvs_mfma(const float* __restrict__ v_pad, const int* __restrict__ v_len,
              const unsigned short* __restrict__ mws,
              const float* __restrict__ den_tile,
              float* __restrict__ num_part,   // [B][KCH][V][D] f32
              float* __restrict__ den_part,   // [B][KCH][V]
              int L, int D, int NT)
{
    const int kblk = blockIdx.x, dcb = blockIdx.y, b = blockIdx.z;
    const int Lv = v_len[b];
    const int chunk = (((Lv + KCH - 1) / KCH) + 63) & ~63;   // 64-aligned
    const int l0 = kblk * chunk;
    if (l0 >= Lv) return;
    const int l1 = min(l0 + chunk, Lv);

    const int tid  = threadIdx.x;
    const int d0   = dcb * DC;
    const int lane = tid & 63;
    const int wave = tid >> 6;

    __shared__ __align__(16) unsigned short smB[2][KS][ST2];   // ~33.5 KB

    const int sd   = tid & 31;    // B-staging: 32 float4 cols
    const int srow = tid >> 5;    //            8 row-groups
    const int fcol = lane & 15, foct = lane >> 4;

    f32x4 acc[4][2];
#pragma unroll
    for (int i = 0; i < 4; ++i) {
        acc[i][0] = f32x4{0.f, 0.f, 0.f, 0.f};
        acc[i][1] = f32x4{0.f, 0.f, 0.f, 0.f};
    }
    float denacc = 0.f;

    const float*  vp_b  = v_pad + (size_t)b * L * D + d0;
    const short8* mws_b = (const short8*)mws + (size_t)b * NT * 8 * 64;
    const float*  dt_b  = den_tile + (size_t)b * NT * VV;

    // prologue: issue tile-0 B loads
    float4 ld[8];
#pragma unroll
    for (int it = 0; it < 8; ++it) {
        const int l = l0 + it * 8 + srow;
        ld[it] = make_float4(0.f, 0.f, 0.f, 0.f);
        if (l < l1)
            ld[it] = *(const float4*)(vp_b + (size_t)l * D + sd * 4);
    }

#define STAGE_TILE(SMB)                                                        \
    _Pragma("unroll")                                                          \
    for (int it = 0; it < 8; ++it) {                                           \
        const int lrow = it * 8 + srow;                                        \
        unsigned* w = (unsigned*)&SMB[lrow][sd * 4];                           \
        w[0] = (unsigned)f2bf(ld[it].x) | ((unsigned)f2bf(ld[it].y) << 16);    \
        w[1] = (unsigned)f2bf(ld[it].z) | ((unsigned)f2bf(ld[it].w) << 16);    \
    }

#define PREFETCH_B(LT)                                                         \
    {                                                                          \
        const int ltn = (LT) + KS;                                             \
        if (ltn < l1) {                                                        \
            _Pragma("unroll")                                                  \
            for (int it = 0; it < 8; ++it) {                                   \
                const int l = ltn + it * 8 + srow;                             \
                ld[it] = make_float4(0.f, 0.f, 0.f, 0.f);                      \
                if (l < l1)                                                    \
                    ld[it] = *(const float4*)(vp_b + (size_t)l * D + sd * 4);  \
            }                                                                  \
        }                                                                      \
    }

#define MFMA_TILE(SMB, LT)                                                     \
    {                                                                          \
        const short8* mt = mws_b + ((size_t)((LT) >> 6)) * 8 * 64;             \
        short8 af[2][4];                                                       \
        _Pragma("unroll")                                                      \
        for (int ks = 0; ks < 2; ++ks)                                         \
            _Pragma("unroll")                                                  \
            for (int mf = 0; mf < 4; ++mf)                                     \
                af[ks][mf] = mt[(ks * 4 + mf) * 64 + lane];                    \
        if (dcb == 0 && tid < VV)                                              \
            denacc += dt_b[(size_t)((LT) >> 6) * VV + tid];                    \
        _Pragma("unroll")                                                      \
        for (int ks = 0; ks < 2; ++ks) {                                       \
            _Pragma("unroll")                                                  \
            for (int nf = 0; nf < 2; ++nf) {                                   \
                const int colx  = wave * 32 + nf * 16 + fcol;                  \
                const int kbase = ks * 32 + foct * 8;                          \
                union { unsigned short h[8]; short8 s; } bf;                   \
                _Pragma("unroll")                                              \
                for (int j = 0; j < 8; ++j)                                    \
                    bf.h[j] = SMB[kbase + j][colx];                            \
                _Pragma("unroll")                                              \
                for (int mf = 0; mf < 4; ++mf)                                 \
                    acc[mf][nf] = __builtin_amdgcn_mfma_f32_16x16x32_bf16(     \
                        af[ks][mf], bf.s, acc[mf][nf], 0, 0, 0);               \
            }                                                                  \
        }                                                                      \
    }

    // main loop: ping-pong LDS, ONE barrier per tile (safe: a wave writes
    // buf p at tile t+2 only after BAR(t+1), which every wave reaches only
    // after finishing its tile-t MFMA — the last reader of buf p).
    int lt = l0;
    for (;;) {
        STAGE_TILE(smB[0]);
        __syncthreads();
        PREFETCH_B(lt);
        MFMA_TILE(smB[0], lt);
        lt += KS; if (lt >= l1) break;

        STAGE_TILE(smB[1]);
        __syncthreads();
        PREFETCH_B(lt);
        MFMA_TILE(smB[1], lt);
        lt += KS; if (lt >= l1) break;
    }

#undef STAGE_TILE
#undef PREFETCH_B
#undef MFMA_TILE

    // ---- den partial ----
    if (dcb == 0 && tid < VV)
        den_part[((size_t)b * KCH + kblk) * VV + tid] = denacc;

    // ---- numerator partials (C/D: col=lane&15, row=(lane>>4)*4+r) ----
    float* basep = num_part + ((size_t)b * KCH + kblk) * VV * (size_t)D + d0 + wave * 32;
#pragma unroll
    for (int mf = 0; mf < 4; ++mf) {
#pragma unroll
        for (int nf = 0; nf < 2; ++nf) {
            const int colx = nf * 16 + fcol;
            const int row0 = mf * 16 + foct * 4;
#pragma unroll
            for (int r = 0; r < 4; ++r)
                basep[(size_t)(row0 + r) * D + colx] = acc[mf][nf][r];
        }
    }
}

// ---------------- reduce ----------------
__global__ __launch_bounds__(256)
void dvs_reduce(const float* __restrict__ num_part,
                const float* __restrict__ den_part,
                const int*   __restrict__ v_len,
                float*       __restrict__ out,
                int D, int total4)
{
    const int idx = blockIdx.x * 256 + threadIdx.x;
    if (idx >= total4) return;
    const int dq4 = D / 4;
    const int d4  = idx % dq4;
    const int bv  = idx / dq4;
    const int b   = bv / VV;
    const int v   = bv - b * VV;

    const int Lv    = v_len[b];
    const int chunk = (((Lv + KCH - 1) / KCH) + 63) & ~63;
    const int nk    = (Lv + chunk - 1) / chunk;      // valid chunk slots

    float  den = 1e-6f;
    float4 num = make_float4(0.f, 0.f, 0.f, 0.f);
    for (int k = 0; k < nk; ++k) {
        den += den_part[((size_t)b * KCH + k) * VV + v];
        const float4 p = ((const float4*)(num_part +
                          (((size_t)b * KCH + k) * VV + v) * (size_t)D))[d4];
        num.x += p.x; num.y += p.y; num.z += p.z; num.w += p.w;
    }
    const float inv = 1.0f / den;
    ((float4*)out)[(size_t)bv * dq4 + d4] =
        make_float4(num.x * inv, num.y * inv, num.z * inv, num.w * inv);
}

extern "C" void kernel_launch(void* const* d_in, const int* in_sizes, int n_in,
                              void* d_out, int out_size, void* d_ws, size_t ws_size,
                              hipStream_t stream)
{
    const float* v_pad     = (const float*)d_in[0];
    const int*   v_len     = (const int*)d_in[1];
    const int*   grid_thws = (const int*)d_in[2];
    const float* centers   = (const float*)d_in[3];
    float*       out       = (float*)d_out;

    const int B  = in_sizes[1];
    const int D  = out_size / (B * VV);
    const int L  = in_sizes[0] / (B * D);
    const int NT = (L + KS - 1) / KS;

    // workspace layout (all 16B-aligned)
    float*          num_part = (float*)d_ws;                               // B*KCH*V*D f32
    float*          den_part = num_part + (size_t)B * KCH * VV * D;        // B*KCH*V
    float*          den_tile = den_part + (size_t)B * KCH * VV;            // B*NT*V
    unsigned short* mws      = (unsigned short*)(den_tile + (size_t)B * NT * VV);

    dim3 gridP(NT, B);
    dvs_prep<<<gridP, 256, 0, stream>>>(v_len, grid_thws, centers, mws,
                                        den_tile, NT);

    dim3 gridG(KCH, D / DC, B);
    dvs_mfma<<<gridG, NTH, 0, stream>>>(v_pad, v_len, mws, den_tile,
                                        num_part, den_part, L, D, NT);

    const int total4 = B * VV * D / 4;
    dvs_reduce<<<(total4 + 255) / 256, 256, 0, stream>>>(num_part, den_part,
                                                         v_len, out, D, total4);
}